// Round 7
// baseline (384.564 us; speedup 1.0000x reference)
//
#include <hip/hip_runtime.h>
#include <hip/hip_bf16.h>
#include <cstdint>
#include <cstddef>

#define D_MODEL 1024
#define D_FF    4096
#define RANK    16
#define NTOK    16384   // B*S = 8*2048

typedef __attribute__((ext_vector_type(8))) __bf16 bf16x8;
typedef __attribute__((ext_vector_type(4))) float  f32x4;

using gas_t = const __attribute__((address_space(1))) void*;
using las_t = __attribute__((address_space(3))) void*;

__device__ __forceinline__ unsigned short f2bf(float f) {
    unsigned int u = __builtin_bit_cast(unsigned int, f);
    u += 0x7fffu + ((u >> 16) & 1u);
    return (unsigned short)(u >> 16);
}

__device__ __forceinline__ void gload_lds16(const unsigned short* g, unsigned short* l) {
    __builtin_amdgcn_global_load_lds((gas_t)g, (las_t)l, 16, 0, 0);
}

// ---- fp32 -> bf16 cast of wi and wo in one dispatch ----
__global__ void cast2_kernel(const float* __restrict__ in1, unsigned short* __restrict__ out1,
                             const float* __restrict__ in2, unsigned short* __restrict__ out2,
                             int n4) {
    int i = blockIdx.x * blockDim.x + threadIdx.x;
    int stride = gridDim.x * blockDim.x;
    for (; i < n4; i += stride) {
        float4 v = reinterpret_cast<const float4*>(in1)[i];
        ushort4 o;
        o.x = f2bf(v.x); o.y = f2bf(v.y); o.z = f2bf(v.z); o.w = f2bf(v.w);
        reinterpret_cast<ushort4*>(out1)[i] = o;
        float4 w = reinterpret_cast<const float4*>(in2)[i];
        ushort4 p;
        p.x = f2bf(w.x); p.y = f2bf(w.y); p.z = f2bf(w.z); p.w = f2bf(w.w);
        reinterpret_cast<ushort4*>(out2)[i] = p;
    }
}

// ---- prep: bcat[f][e*16+r] and acatg[e*16+r][d] (bf16 casts of selected experts) ----
__global__ void prep_kernel(const float* __restrict__ Bs, const float* __restrict__ As,
                            const int* __restrict__ idx,
                            unsigned short* __restrict__ bcat, unsigned short* __restrict__ acatg) {
    int i = blockIdx.x * blockDim.x + threadIdx.x;
    if (i < D_FF * 32) {
        int f = i >> 5, kk = i & 31, e = kk >> 4, r = kk & 15;
        bcat[i] = f2bf(Bs[(size_t)idx[e] * D_FF * RANK + (size_t)f * RANK + r]);
    } else {
        int j = i - D_FF * 32;                 // < 32*1024
        int row = j >> 10, col = j & 1023, e = row >> 4, r = row & 15;
        acatg[j] = f2bf(As[(size_t)idx[e] * RANK * D_MODEL + r * D_MODEL + col]);
    }
}

// ---- t = h @ A_cat^T via MFMA; fuses h->bf16 cast. 64 tokens/block, 4 waves ----
__global__ void lora_t_v2(const float* __restrict__ h,
                          const unsigned short* __restrict__ acatg,
                          unsigned short* __restrict__ tcat,
                          unsigned short* __restrict__ hbf) {
    const int tid = threadIdx.x, lane = tid & 63, w = tid >> 6;
    const int tok0 = blockIdx.x * 64 + w * 16;
    const int lr = lane & 15, kc = lane >> 4;
    f32x4 acc0 = {}, acc1 = {};
    const size_t rowoff = (size_t)(tok0 + lr) * D_MODEL;
    #pragma unroll 4
    for (int kt = 0; kt < 32; ++kt) {
        const int k0 = kt * 32 + kc * 8;
        float4 u0 = *reinterpret_cast<const float4*>(h + rowoff + k0);
        float4 u1 = *reinterpret_cast<const float4*>(h + rowoff + k0 + 4);
        union { bf16x8 v; unsigned short s[8]; } af;
        af.s[0] = f2bf(u0.x); af.s[1] = f2bf(u0.y); af.s[2] = f2bf(u0.z); af.s[3] = f2bf(u0.w);
        af.s[4] = f2bf(u1.x); af.s[5] = f2bf(u1.y); af.s[6] = f2bf(u1.z); af.s[7] = f2bf(u1.w);
        *reinterpret_cast<bf16x8*>(&hbf[rowoff + k0]) = af.v;
        bf16x8 b0 = *reinterpret_cast<const bf16x8*>(&acatg[(size_t)lr * D_MODEL + k0]);
        bf16x8 b1 = *reinterpret_cast<const bf16x8*>(&acatg[(size_t)(16 + lr) * D_MODEL + k0]);
        acc0 = __builtin_amdgcn_mfma_f32_16x16x32_bf16(af.v, b0, acc0, 0, 0, 0);
        acc1 = __builtin_amdgcn_mfma_f32_16x16x32_bf16(af.v, b1, acc1, 0, 0, 0);
    }
    #pragma unroll
    for (int j = 0; j < 4; ++j) {
        tcat[(size_t)(tok0 + kc * 4 + j) * 32 + lr]      = f2bf(acc0[j]);
        tcat[(size_t)(tok0 + kc * 4 + j) * 32 + 16 + lr] = f2bf(acc1[j]);
    }
}

// ============================================================================
// 256x256 8-phase GEMM. Barrier/wait/stage skeleton BYTE-IDENTICAL to the
// proven round-4 schedule (149 us gemm1, conflicts 0), incl. P4/P8's
// MFMA -> WAIT_VM(4) -> BAR order. Single change: P1/P2/P5/P6 issue the NEXT
// phase's ds_reads (from already-published buffers) after their WAIT_LGKM,
// pinned above the MFMA cluster by sched_barrier(0), so those reads execute
// in the MFMA shadow. P3/P4/P7/P8 start with zero reads. Two A-frag register
// sets (aF=quad0, aF2=quad1). Lifetimes: every lookahead read completes at
// the consuming wave's next WAIT_LGKM, which precedes (via barrier) any
// overwriting stage issue.
// ============================================================================
template<int KDIM, int EPI, int OSTRIDE, int GN>
__launch_bounds__(512, 2)
__global__ void gemm256(const unsigned short* __restrict__ A,
                        const unsigned short* __restrict__ Bm,
                        float* __restrict__ outF,
                        unsigned short* __restrict__ outBf,
                        const unsigned short* __restrict__ tcat,
                        const unsigned short* __restrict__ bcat,
                        const float* __restrict__ topv) {
    __shared__ unsigned short lds[2][2][2][128 * 64];
    const int tid  = threadIdx.x;
    const int lane = tid & 63;
    const int wid  = tid >> 6;        // 0..7
    const int wr   = wid >> 2;        // 0..1
    const int wc   = wid & 3;         // 0..3
    const int lr   = lane & 15;
    const int hi   = lane >> 4;       // 0..3
    const int swz  = (lane & 7) << 3; // read-side col swizzle

    // bijective XCD swizzle (nwg % 8 == 0 for both launches)
    const int nwg  = gridDim.x;
    const int orig = blockIdx.x;
    const int wg   = (orig & 7) * (nwg >> 3) + (orig >> 3);
    const int bm0  = (wg / GN) * 256;
    const int bn0  = (wg % GN) * 256;

    constexpr int NKT = KDIM / 64;
    constexpr int NT2 = NKT / 2;

    f32x4 acc[8][4] = {};
    bf16x8 aF[8], aF2[8], b0[4], b1[4];

    auto stage = [&](int buf, int mat, int half, const unsigned short* src, int kt) {
        const int row0 = (mat == 0 ? bm0 : bn0) + half * 128;
        const int k0 = kt * 64;
        #pragma unroll
        for (int p = 0; p < 2; ++p) {
            const int L = p * 8192 + tid * 16;           // byte offset in half-tile
            const int r = L >> 7;                        // row (128B rows)
            const int c = (L & 127) >> 1;                // element col of linear slot
            const int gc = k0 + (c ^ ((r & 7) << 3));    // inverse-swizzled global col
            gload_lds16(src + (size_t)(row0 + r) * KDIM + gc,
                        &lds[buf][mat][half][0] + (L >> 1));
        }
    };
    auto readA = [&](int buf, int qm, bf16x8* dst) {
        #pragma unroll
        for (int fr = 0; fr < 4; ++fr)
            #pragma unroll
            for (int ks = 0; ks < 2; ++ks)
                dst[fr * 2 + ks] = *reinterpret_cast<const bf16x8*>(
                    &lds[buf][0][wr][(qm * 64 + fr * 16 + lr) * 64 + ((ks * 32 + hi * 8) ^ swz)]);
    };
    auto readB = [&](int buf, int qn, bf16x8* bb) {
        #pragma unroll
        for (int fc = 0; fc < 2; ++fc)
            #pragma unroll
            for (int ks = 0; ks < 2; ++ks)
                bb[fc * 2 + ks] = *reinterpret_cast<const bf16x8*>(
                    &lds[buf][1][wc >> 1][((wc & 1) * 64 + qn * 32 + fc * 16 + lr) * 64
                                          + ((ks * 32 + hi * 8) ^ swz)]);
    };
    auto mfma16 = [&](const bf16x8* aa, int qm, int qn, const bf16x8* bb) {
        #pragma unroll
        for (int fr = 0; fr < 4; ++fr)
            #pragma unroll
            for (int fc = 0; fc < 2; ++fc)
                #pragma unroll
                for (int ks = 0; ks < 2; ++ks)
                    acc[qm * 4 + fr][qn * 2 + fc] = __builtin_amdgcn_mfma_f32_16x16x32_bf16(
                        aa[fr * 2 + ks], bb[fc * 2 + ks], acc[qm * 4 + fr][qn * 2 + fc], 0, 0, 0);
    };

#define BAR() __builtin_amdgcn_s_barrier()
#define SCHED0() __builtin_amdgcn_sched_barrier(0)
#define WAIT_LGKM() do { asm volatile("s_waitcnt lgkmcnt(0)" ::: "memory"); SCHED0(); } while (0)
#define WAIT_VM(n) do { asm volatile("s_waitcnt vmcnt(" #n ")" ::: "memory"); SCHED0(); } while (0)
#define PRIO_MFMA(aa, qm, qn, bb) do { __builtin_amdgcn_s_setprio(1); mfma16(aa, qm, qn, bb); \
                                       __builtin_amdgcn_s_setprio(0); } while (0)

    // Prologue: tile0 (all 4 halves) -> buf0; tile1 B-halves -> buf1.
    stage(0, 0, 0, A, 0);  stage(0, 0, 1, A, 0);
    stage(0, 1, 0, Bm, 0); stage(0, 1, 1, Bm, 0);
    stage(1, 1, 0, Bm, 1); stage(1, 1, 1, Bm, 1);
    WAIT_VM(4);
    BAR();

    #pragma unroll 1
    for (int it = 0; it < NT2; ++it) {
        const int t1 = 2 * it + 1;
        const int t2 = (2 * it + 2 < NKT) ? 2 * it + 2 : NKT - 1;  // clamp: dummy, never read
        const int t3 = (2 * it + 3 < NKT) ? 2 * it + 3 : NKT - 1;
        // P1: reads {aF q0, b0} (buf0, published at prev P8/prologue); stage buf1.A-top;
        //     lookahead b1 (P2's operand) in MFMA shadow
        readA(0, 0, aF); readB(0, 0, b0);
        stage(1, 0, 0, A, t1);
        BAR(); WAIT_LGKM();
        readB(0, 1, b1); SCHED0();
        PRIO_MFMA(aF, 0, 0, b0);
        BAR();
        // P2: stage buf1.A-bot; lookahead aF2 (P3/P4's A-quad) in MFMA shadow
        stage(1, 0, 1, A, t1);
        BAR(); WAIT_LGKM();
        readA(0, 1, aF2); SCHED0();
        PRIO_MFMA(aF, 0, 1, b1);
        BAR();
        // P3: no reads (aF2,b0 ready); stage buf0.B-top (t2)  [buf0.B free after P2]
        stage(0, 1, 0, Bm, t2);
        BAR(); WAIT_LGKM();
        PRIO_MFMA(aF2, 1, 0, b0);
        BAR();
        // P4: no reads; stage buf0.B-bot (t2); MFMA -> vmcnt(4) -> BAR (round-4 order;
        //     buf1 t1 fully staged and published at this BAR)
        stage(0, 1, 1, Bm, t2);
        BAR(); PRIO_MFMA(aF2, 1, 1, b1); WAIT_VM(4); BAR();
        // P5: reads {aF q0, b0} from buf1; stage buf0.A-top (t2); lookahead b1
        readA(1, 0, aF); readB(1, 0, b0);
        stage(0, 0, 0, A, t2);
        BAR(); WAIT_LGKM();
        readB(1, 1, b1); SCHED0();
        PRIO_MFMA(aF, 0, 0, b0);
        BAR();
        // P6: stage buf0.A-bot (t2); lookahead aF2
        stage(0, 0, 1, A, t2);
        BAR(); WAIT_LGKM();
        readA(1, 1, aF2); SCHED0();
        PRIO_MFMA(aF, 0, 1, b1);
        BAR();
        // P7: no reads; stage buf1.B-top (t3)  [buf1.B free after P6]
        stage(1, 1, 0, Bm, t3);
        BAR(); WAIT_LGKM();
        PRIO_MFMA(aF2, 1, 0, b0);
        BAR();
        // P8: no reads; stage buf1.B-bot (t3); MFMA -> vmcnt(4) -> BAR
        stage(1, 1, 1, Bm, t3);
        BAR(); PRIO_MFMA(aF2, 1, 1, b1); WAIT_VM(4); BAR();
    }
    asm volatile("s_waitcnt vmcnt(0)" ::: "memory");
    SCHED0();
    BAR();

    // ---- epilogue ----
    const int rbase = bm0 + wr * 128 + hi * 4;
    const int cbase = bn0 + wc * 64 + lr;

    if constexpr (EPI == 1) {
        const float v0 = topv[0], v1 = topv[1];
        const bf16x8 z8 = {};
        bf16x8 bl0[4], bl1[4];
        #pragma unroll
        for (int ni = 0; ni < 4; ++ni) {
            const int f = cbase + ni * 16;
            bf16x8 bfull = *reinterpret_cast<const bf16x8*>(&bcat[(size_t)f * 32 + hi * 8]);
            bl0[ni] = (hi < 2) ? bfull : z8;   // [B0 | 0]
            bl1[ni] = (hi < 2) ? z8 : bfull;   // [0 | B1]
        }
        #pragma unroll
        for (int mi = 0; mi < 8; ++mi) {
            const int mrow = bm0 + wr * 128 + mi * 16 + lr;
            const bf16x8 alo = *reinterpret_cast<const bf16x8*>(&tcat[(size_t)mrow * 32 + hi * 8]);
            #pragma unroll
            for (int ni = 0; ni < 4; ++ni) {
                const f32x4 zz = {};
                f32x4 l0 = __builtin_amdgcn_mfma_f32_16x16x32_bf16(alo, bl0[ni], zz, 0, 0, 0);
                f32x4 l1 = __builtin_amdgcn_mfma_f32_16x16x32_bf16(alo, bl1[ni], zz, 0, 0, 0);
                #pragma unroll
                for (int j = 0; j < 4; ++j) {
                    float z = acc[mi][ni][j];
                    float c = v0 * fmaxf(z + l0[j], 0.f) + v1 * fmaxf(z + l1[j], 0.f);
                    outBf[(size_t)(rbase + mi * 16 + j) * OSTRIDE + cbase + ni * 16] = f2bf(c);
                }
            }
        }
    } else {
        #pragma unroll
        for (int mi = 0; mi < 8; ++mi)
            #pragma unroll
            for (int ni = 0; ni < 4; ++ni)
                #pragma unroll
                for (int j = 0; j < 4; ++j)
                    outF[(size_t)(rbase + mi * 16 + j) * OSTRIDE + cbase + ni * 16] = acc[mi][ni][j];
    }
#undef BAR
#undef SCHED0
#undef WAIT_LGKM
#undef WAIT_VM
#undef PRIO_MFMA
}

extern "C" void kernel_launch(void* const* d_in, const int* in_sizes, int n_in,
                              void* d_out, int out_size, void* d_ws, size_t ws_size,
                              hipStream_t stream) {
    const float* h    = (const float*)d_in[0];
    const float* wi   = (const float*)d_in[1];
    const float* wo   = (const float*)d_in[2];
    const float* As   = (const float*)d_in[3];
    const float* Bs   = (const float*)d_in[4];
    const int*   idx  = (const int*)d_in[5];
    const float* topv = (const float*)d_in[6];
    float* out = (float*)d_out;

    char* ws = (char*)d_ws;
    unsigned short* hbf   = (unsigned short*)(ws);                      // 32MB
    unsigned short* wibf  = (unsigned short*)(ws + 33554432);           // 8MB
    unsigned short* wobf  = (unsigned short*)(ws + 41943040);           // 8MB
    unsigned short* tcat  = (unsigned short*)(ws + 50331648);           // 1MB
    unsigned short* bcat  = (unsigned short*)(ws + 51380224);           // 256KB
    unsigned short* acatg = (unsigned short*)(ws + 51642368);           // 64KB
    unsigned short* comb  = (unsigned short*)(ws + 51707904);           // 128MB

    prep_kernel<<<640, 256, 0, stream>>>(Bs, As, idx, bcat, acatg);
    lora_t_v2<<<NTOK / 64, 256, 0, stream>>>(h, acatg, tcat, hbf);      // + h->bf16 cast
    cast2_kernel<<<1024, 256, 0, stream>>>(wi, wibf, wo, wobf, (D_FF * D_MODEL) / 4);

    // gemm1: comb = sum_k v_k * relu(h@Wi^T + t_k@B_k^T)   [16384 x 4096] bf16
    gemm256<D_MODEL, 1, D_FF, 16><<<dim3(64 * 16), 512, 0, stream>>>(
        hbf, wibf, nullptr, comb, tcat, bcat, topv);
    // gemm2: out = comb @ Wo^T                              [16384 x 1024] fp32
    gemm256<D_FF, 0, D_MODEL, 4><<<dim3(64 * 4), 512, 0, stream>>>(
        comb, wobf, out, nullptr, nullptr, nullptr, nullptr);
}

// Round 8
// 283.057 us; speedup vs baseline: 1.3586x; 1.3586x over previous
//
#include <hip/hip_runtime.h>
#include <hip/hip_bf16.h>
#include <cstdint>
#include <cstddef>

#define D_MODEL 1024
#define D_FF    4096
#define RANK    16
#define NTOK    16384   // B*S = 8*2048

typedef __attribute__((ext_vector_type(8))) __bf16 bf16x8;
typedef __attribute__((ext_vector_type(4))) float  f32x4;

using gas_t = const __attribute__((address_space(1))) void*;
using las_t = __attribute__((address_space(3))) void*;

__device__ __forceinline__ unsigned short f2bf(float f) {
    unsigned int u = __builtin_bit_cast(unsigned int, f);
    u += 0x7fffu + ((u >> 16) & 1u);
    return (unsigned short)(u >> 16);
}

__device__ __forceinline__ void gload_lds16(const unsigned short* g, unsigned short* l) {
    __builtin_amdgcn_global_load_lds((gas_t)g, (las_t)l, 16, 0, 0);
}

// ---- combined: wi/wo fp32->bf16 casts (blocks 0..1023) + bcat/acatg prep (blocks 1024..1663) ----
__global__ void prep_cast_kernel(const float* __restrict__ wi, unsigned short* __restrict__ wibf,
                                 const float* __restrict__ wo, unsigned short* __restrict__ wobf,
                                 const float* __restrict__ Bs, const float* __restrict__ As,
                                 const int* __restrict__ idx,
                                 unsigned short* __restrict__ bcat, unsigned short* __restrict__ acatg) {
    const int bid = blockIdx.x;
    if (bid < 1024) {
        const int n4 = (D_FF * D_MODEL) / 4;
        int i = bid * blockDim.x + threadIdx.x;
        const int stride = 1024 * blockDim.x;
        for (; i < n4; i += stride) {
            float4 v = reinterpret_cast<const float4*>(wi)[i];
            ushort4 o;
            o.x = f2bf(v.x); o.y = f2bf(v.y); o.z = f2bf(v.z); o.w = f2bf(v.w);
            reinterpret_cast<ushort4*>(wibf)[i] = o;
            float4 w = reinterpret_cast<const float4*>(wo)[i];
            ushort4 p;
            p.x = f2bf(w.x); p.y = f2bf(w.y); p.z = f2bf(w.z); p.w = f2bf(w.w);
            reinterpret_cast<ushort4*>(wobf)[i] = p;
        }
    } else {
        int i = (bid - 1024) * blockDim.x + threadIdx.x;   // < 640*256 = D_FF*32 + 32*1024
        if (i < D_FF * 32) {
            int f = i >> 5, kk = i & 31, e = kk >> 4, r = kk & 15;
            bcat[i] = f2bf(Bs[(size_t)idx[e] * D_FF * RANK + (size_t)f * RANK + r]);
        } else {
            int j = i - D_FF * 32;                 // < 32*1024
            int row = j >> 10, col = j & 1023, e = row >> 4, r = row & 15;
            acatg[j] = f2bf(As[(size_t)idx[e] * RANK * D_MODEL + r * D_MODEL + col]);
        }
    }
}

// ---- t = h @ A_cat^T via MFMA; fuses h->bf16 cast. 64 tokens/block, 4 waves ----
__global__ void lora_t_v2(const float* __restrict__ h,
                          const unsigned short* __restrict__ acatg,
                          unsigned short* __restrict__ tcat,
                          unsigned short* __restrict__ hbf) {
    const int tid = threadIdx.x, lane = tid & 63, w = tid >> 6;
    const int tok0 = blockIdx.x * 64 + w * 16;
    const int lr = lane & 15, kc = lane >> 4;
    f32x4 acc0 = {}, acc1 = {};
    const size_t rowoff = (size_t)(tok0 + lr) * D_MODEL;
    #pragma unroll 4
    for (int kt = 0; kt < 32; ++kt) {
        const int k0 = kt * 32 + kc * 8;
        float4 u0 = *reinterpret_cast<const float4*>(h + rowoff + k0);
        float4 u1 = *reinterpret_cast<const float4*>(h + rowoff + k0 + 4);
        union { bf16x8 v; unsigned short s[8]; } af;
        af.s[0] = f2bf(u0.x); af.s[1] = f2bf(u0.y); af.s[2] = f2bf(u0.z); af.s[3] = f2bf(u0.w);
        af.s[4] = f2bf(u1.x); af.s[5] = f2bf(u1.y); af.s[6] = f2bf(u1.z); af.s[7] = f2bf(u1.w);
        *reinterpret_cast<bf16x8*>(&hbf[rowoff + k0]) = af.v;
        bf16x8 b0 = *reinterpret_cast<const bf16x8*>(&acatg[(size_t)lr * D_MODEL + k0]);
        bf16x8 b1 = *reinterpret_cast<const bf16x8*>(&acatg[(size_t)(16 + lr) * D_MODEL + k0]);
        acc0 = __builtin_amdgcn_mfma_f32_16x16x32_bf16(af.v, b0, acc0, 0, 0, 0);
        acc1 = __builtin_amdgcn_mfma_f32_16x16x32_bf16(af.v, b1, acc1, 0, 0, 0);
    }
    #pragma unroll
    for (int j = 0; j < 4; ++j) {
        tcat[(size_t)(tok0 + kc * 4 + j) * 32 + lr]      = f2bf(acc0[j]);
        tcat[(size_t)(tok0 + kc * 4 + j) * 32 + 16 + lr] = f2bf(acc1[j]);
    }
}

// ============================================================================
// 256x256 8-phase GEMM — round-4 proven schedule, byte-identical.
// (gemm1 149 us / MfmaUtil 42% / bank-conflict 0; manual lookahead and
// persistence both measured as regressions in rounds 3/5/6/7 — the compiler's
// own interleave of reads and MFMAs within this skeleton is the optimum.)
// ============================================================================
template<int KDIM, int EPI, int OSTRIDE, int GN>
__launch_bounds__(512, 2)
__global__ void gemm256(const unsigned short* __restrict__ A,
                        const unsigned short* __restrict__ Bm,
                        float* __restrict__ outF,
                        unsigned short* __restrict__ outBf,
                        const unsigned short* __restrict__ tcat,
                        const unsigned short* __restrict__ bcat,
                        const float* __restrict__ topv) {
    __shared__ unsigned short lds[2][2][2][128 * 64];
    const int tid  = threadIdx.x;
    const int lane = tid & 63;
    const int wid  = tid >> 6;        // 0..7
    const int wr   = wid >> 2;        // 0..1
    const int wc   = wid & 3;         // 0..3
    const int lr   = lane & 15;
    const int hi   = lane >> 4;       // 0..3
    const int swz  = (lane & 7) << 3; // read-side col swizzle

    // bijective XCD swizzle (nwg % 8 == 0 for both launches)
    const int nwg  = gridDim.x;
    const int orig = blockIdx.x;
    const int wg   = (orig & 7) * (nwg >> 3) + (orig >> 3);
    const int bm0  = (wg / GN) * 256;
    const int bn0  = (wg % GN) * 256;

    constexpr int NKT = KDIM / 64;
    constexpr int NT2 = NKT / 2;

    f32x4 acc[8][4] = {};
    bf16x8 aF[8], b0[4], b1[4];

    auto stage = [&](int buf, int mat, int half, const unsigned short* src, int kt) {
        const int row0 = (mat == 0 ? bm0 : bn0) + half * 128;
        const int k0 = kt * 64;
        #pragma unroll
        for (int p = 0; p < 2; ++p) {
            const int L = p * 8192 + tid * 16;           // byte offset in half-tile
            const int r = L >> 7;                        // row (128B rows)
            const int c = (L & 127) >> 1;                // element col of linear slot
            const int gc = k0 + (c ^ ((r & 7) << 3));    // inverse-swizzled global col
            gload_lds16(src + (size_t)(row0 + r) * KDIM + gc,
                        &lds[buf][mat][half][0] + (L >> 1));
        }
    };
    auto readA = [&](int buf, int qm) {
        #pragma unroll
        for (int fr = 0; fr < 4; ++fr)
            #pragma unroll
            for (int ks = 0; ks < 2; ++ks)
                aF[fr * 2 + ks] = *reinterpret_cast<const bf16x8*>(
                    &lds[buf][0][wr][(qm * 64 + fr * 16 + lr) * 64 + ((ks * 32 + hi * 8) ^ swz)]);
    };
    auto readB = [&](int buf, int qn, bf16x8* bb) {
        #pragma unroll
        for (int fc = 0; fc < 2; ++fc)
            #pragma unroll
            for (int ks = 0; ks < 2; ++ks)
                bb[fc * 2 + ks] = *reinterpret_cast<const bf16x8*>(
                    &lds[buf][1][wc >> 1][((wc & 1) * 64 + qn * 32 + fc * 16 + lr) * 64
                                          + ((ks * 32 + hi * 8) ^ swz)]);
    };
    auto mfma16 = [&](int qm, int qn, const bf16x8* bb) {
        #pragma unroll
        for (int fr = 0; fr < 4; ++fr)
            #pragma unroll
            for (int fc = 0; fc < 2; ++fc)
                #pragma unroll
                for (int ks = 0; ks < 2; ++ks)
                    acc[qm * 4 + fr][qn * 2 + fc] = __builtin_amdgcn_mfma_f32_16x16x32_bf16(
                        aF[fr * 2 + ks], bb[fc * 2 + ks], acc[qm * 4 + fr][qn * 2 + fc], 0, 0, 0);
    };

#define BAR() __builtin_amdgcn_s_barrier()
#define WAIT_LGKM() do { asm volatile("s_waitcnt lgkmcnt(0)" ::: "memory"); \
                         __builtin_amdgcn_sched_barrier(0); } while (0)
#define WAIT_VM(n) do { asm volatile("s_waitcnt vmcnt(" #n ")" ::: "memory"); \
                        __builtin_amdgcn_sched_barrier(0); } while (0)
#define PRIO_MFMA(qm, qn, bb) do { __builtin_amdgcn_s_setprio(1); mfma16(qm, qn, bb); \
                                   __builtin_amdgcn_s_setprio(0); } while (0)

    // Prologue: tile0 (all 4 halves) -> bufA; tile1 B-halves -> bufB.
    stage(0, 0, 0, A, 0);  stage(0, 0, 1, A, 0);
    stage(0, 1, 0, Bm, 0); stage(0, 1, 1, Bm, 0);
    stage(1, 1, 0, Bm, 1); stage(1, 1, 1, Bm, 1);
    WAIT_VM(4);
    BAR();

    #pragma unroll 1
    for (int it = 0; it < NT2; ++it) {
        const int t1 = 2 * it + 1;
        const int t2 = (2 * it + 2 < NKT) ? 2 * it + 2 : NKT - 1;  // clamp: dummy, never read
        const int t3 = (2 * it + 3 < NKT) ? 2 * it + 3 : NKT - 1;
        // P1: quad(0,0) from bufA; stage bufB.A-top (tile t1)
        readA(0, 0); readB(0, 0, b0);
        stage(1, 0, 0, A, t1);
        BAR(); WAIT_LGKM(); PRIO_MFMA(0, 0, b0); BAR();
        // P2: quad(0,1); stage bufB.A-bot (t1)
        readB(0, 1, b1);
        stage(1, 0, 1, A, t1);
        BAR(); WAIT_LGKM(); PRIO_MFMA(0, 1, b1); BAR();
        // P3: quad(1,0); stage bufA.B-top (t2)  [bufA.B free after P2]
        readA(0, 1);
        stage(0, 1, 0, Bm, t2);
        BAR(); WAIT_LGKM(); PRIO_MFMA(1, 0, b0); BAR();
        // P4: quad(1,1); stage bufA.B-bot (t2); vmcnt(4) -> tile t1 fully staged
        stage(0, 1, 1, Bm, t2);
        BAR(); PRIO_MFMA(1, 1, b1); WAIT_VM(4); BAR();
        // P5: quad(0,0) from bufB; stage bufA.A-top (t2)  [bufA.A free after P3]
        readA(1, 0); readB(1, 0, b0);
        stage(0, 0, 0, A, t2);
        BAR(); WAIT_LGKM(); PRIO_MFMA(0, 0, b0); BAR();
        // P6: quad(0,1); stage bufA.A-bot (t2)
        readB(1, 1, b1);
        stage(0, 0, 1, A, t2);
        BAR(); WAIT_LGKM(); PRIO_MFMA(0, 1, b1); BAR();
        // P7: quad(1,0); stage bufB.B-top (t3)  [bufB.B free after P6]
        readA(1, 1);
        stage(1, 1, 0, Bm, t3);
        BAR(); WAIT_LGKM(); PRIO_MFMA(1, 0, b0); BAR();
        // P8: quad(1,1); stage bufB.B-bot (t3); vmcnt(4) -> tile t2 fully staged
        stage(1, 1, 1, Bm, t3);
        BAR(); PRIO_MFMA(1, 1, b1); WAIT_VM(4); BAR();
    }
    asm volatile("s_waitcnt vmcnt(0)" ::: "memory");
    __builtin_amdgcn_sched_barrier(0);
    BAR();

    // ---- epilogue ----
    const int rbase = bm0 + wr * 128 + hi * 4;
    const int cbase = bn0 + wc * 64 + lr;

    if constexpr (EPI == 1) {
        const float v0 = topv[0], v1 = topv[1];
        const bf16x8 z8 = {};
        bf16x8 bl0[4], bl1[4];
        #pragma unroll
        for (int ni = 0; ni < 4; ++ni) {
            const int f = cbase + ni * 16;
            bf16x8 bfull = *reinterpret_cast<const bf16x8*>(&bcat[(size_t)f * 32 + hi * 8]);
            bl0[ni] = (hi < 2) ? bfull : z8;   // [B0 | 0]
            bl1[ni] = (hi < 2) ? z8 : bfull;   // [0 | B1]
        }
        #pragma unroll
        for (int mi = 0; mi < 8; ++mi) {
            const int mrow = bm0 + wr * 128 + mi * 16 + lr;
            const bf16x8 alo = *reinterpret_cast<const bf16x8*>(&tcat[(size_t)mrow * 32 + hi * 8]);
            #pragma unroll
            for (int ni = 0; ni < 4; ++ni) {
                const f32x4 zz = {};
                f32x4 l0 = __builtin_amdgcn_mfma_f32_16x16x32_bf16(alo, bl0[ni], zz, 0, 0, 0);
                f32x4 l1 = __builtin_amdgcn_mfma_f32_16x16x32_bf16(alo, bl1[ni], zz, 0, 0, 0);
                #pragma unroll
                for (int j = 0; j < 4; ++j) {
                    float z = acc[mi][ni][j];
                    float c = v0 * fmaxf(z + l0[j], 0.f) + v1 * fmaxf(z + l1[j], 0.f);
                    outBf[(size_t)(rbase + mi * 16 + j) * OSTRIDE + cbase + ni * 16] = f2bf(c);
                }
            }
        }
    } else {
        #pragma unroll
        for (int mi = 0; mi < 8; ++mi)
            #pragma unroll
            for (int ni = 0; ni < 4; ++ni)
                #pragma unroll
                for (int j = 0; j < 4; ++j)
                    outF[(size_t)(rbase + mi * 16 + j) * OSTRIDE + cbase + ni * 16] = acc[mi][ni][j];
    }
#undef BAR
#undef WAIT_LGKM
#undef WAIT_VM
#undef PRIO_MFMA
}

extern "C" void kernel_launch(void* const* d_in, const int* in_sizes, int n_in,
                              void* d_out, int out_size, void* d_ws, size_t ws_size,
                              hipStream_t stream) {
    const float* h    = (const float*)d_in[0];
    const float* wi   = (const float*)d_in[1];
    const float* wo   = (const float*)d_in[2];
    const float* As   = (const float*)d_in[3];
    const float* Bs   = (const float*)d_in[4];
    const int*   idx  = (const int*)d_in[5];
    const float* topv = (const float*)d_in[6];
    float* out = (float*)d_out;

    char* ws = (char*)d_ws;
    unsigned short* hbf   = (unsigned short*)(ws);                      // 32MB
    unsigned short* wibf  = (unsigned short*)(ws + 33554432);           // 8MB
    unsigned short* wobf  = (unsigned short*)(ws + 41943040);           // 8MB
    unsigned short* tcat  = (unsigned short*)(ws + 50331648);           // 1MB
    unsigned short* bcat  = (unsigned short*)(ws + 51380224);           // 256KB
    unsigned short* acatg = (unsigned short*)(ws + 51642368);           // 64KB
    unsigned short* comb  = (unsigned short*)(ws + 51707904);           // 128MB

    prep_cast_kernel<<<1664, 256, 0, stream>>>(wi, wibf, wo, wobf, Bs, As, idx, bcat, acatg);
    lora_t_v2<<<NTOK / 64, 256, 0, stream>>>(h, acatg, tcat, hbf);      // + h->bf16 cast

    // gemm1: comb = sum_k v_k * relu(h@Wi^T + t_k@B_k^T)   [16384 x 4096] bf16
    gemm256<D_MODEL, 1, D_FF, 16><<<dim3(64 * 16), 512, 0, stream>>>(
        hbf, wibf, nullptr, comb, tcat, bcat, topv);
    // gemm2: out = comb @ Wo^T                              [16384 x 1024] fp32
    gemm256<D_FF, 0, D_MODEL, 4><<<dim3(64 * 4), 512, 0, stream>>>(
        comb, wobf, out, nullptr, nullptr, nullptr, nullptr);
}